// Round 12
// baseline (508.663 us; speedup 1.0000x reference)
//
#include <hip/hip_runtime.h>

#define N_NODES 100000
#define N_EDGES 1600000
#define IN_DIM 128
#define HIDDEN 256
#define EMBED 64
#define K_STEPS 10

// binning geometry
#define NPB_SHIFT 10
#define NPB 1024                    // nodes per bucket
#define NBUCK 98                    // ceil(100000/1024)
#define TILE 2048                   // edges per bin tile
#define NTILES 782                  // ceil(1.6M/2048)
#define CAP 64                      // slots per (tile,bucket); mean 20.9 -> 9.6 sigma margin

typedef unsigned int u32;
typedef unsigned short u16;
using bf16x8 = __attribute__((ext_vector_type(8))) short;
using f32x4  = __attribute__((ext_vector_type(4))) float;

__device__ __forceinline__ float bflo(u32 u) { return __uint_as_float(u << 16); }
__device__ __forceinline__ float bfhi(u32 u) { return __uint_as_float(u & 0xffff0000u); }
__device__ __forceinline__ u16 f2bf(float f) {   // round-to-nearest-even
    u32 u = __float_as_uint(f);
    u += 0x7fffu + ((u >> 16) & 1u);
    return (u16)(u >> 16);
}

// ---------------- weight prep: transpose + bf16 convert ----------------
__global__ void conv_weights(const float* __restrict__ W1, const float* __restrict__ W2,
                             u16* __restrict__ W1T, u16* __restrict__ W2T)
{
    int i = blockIdx.x * 256 + threadIdx.x;
    if (i < IN_DIM * HIDDEN) {
        int n = i / IN_DIM, k = i % IN_DIM;
        W1T[i] = f2bf(W1[k * HIDDEN + n]);
    }
    int j = i - IN_DIM * HIDDEN;
    if (j >= 0 && j < HIDDEN * EMBED) {
        int n = j / HIDDEN, k = j % HIDDEN;
        W2T[j] = f2bf(W2[k * EMBED + n]);
    }
}

// ---------------- fused MLP via bf16 MFMA; 32-row tile (R11 version, frozen) ----------------
__global__ __launch_bounds__(256) void mlp_mfma(
    const float* __restrict__ x, const u16* __restrict__ W1T,
    const float* __restrict__ b1, const u16* __restrict__ W2T,
    const float* __restrict__ b2, const float* __restrict__ dinv,
    u16* __restrict__ x0bf, u16* __restrict__ g0bf, int n)
{
    __shared__ u16 Xs[32][136];    // 8.7 KB
    __shared__ u16 H1s[32][264];   // 16.9 KB
    int t = threadIdx.x;
    int rowBase = blockIdx.x * 32;
    int lane = t & 63, w = t >> 6;
    int lr = lane & 15, kg = lane >> 4;

    {
        float4 v[4];
        #pragma unroll
        for (int it = 0; it < 4; ++it) {
            int i = t + it * 256;
            int row = i >> 5, c4 = (i & 31) * 4;
            v[it] = make_float4(0.f, 0.f, 0.f, 0.f);
            if (rowBase + row < n)
                v[it] = *(const float4*)(x + (size_t)(rowBase + row) * IN_DIM + c4);
        }
        #pragma unroll
        for (int it = 0; it < 4; ++it) {
            int i = t + it * 256;
            int row = i >> 5, c4 = (i & 31) * 4;
            Xs[row][c4 + 0] = f2bf(v[it].x); Xs[row][c4 + 1] = f2bf(v[it].y);
            Xs[row][c4 + 2] = f2bf(v[it].z); Xs[row][c4 + 3] = f2bf(v[it].w);
        }
    }

    int n0 = w * 64;
    bf16x8 ball[4][4];
    #pragma unroll
    for (int k = 0; k < 4; ++k)
        #pragma unroll
        for (int nn = 0; nn < 4; ++nn)
            ball[k][nn] = *(const bf16x8*)(W1T + (size_t)(n0 + nn * 16 + lr) * IN_DIM + k * 32 + kg * 8);
    __syncthreads();

    {
        f32x4 acc[2][4];
        #pragma unroll
        for (int m = 0; m < 2; ++m)
            #pragma unroll
            for (int nn = 0; nn < 4; ++nn) acc[m][nn] = (f32x4){0.f, 0.f, 0.f, 0.f};
        #pragma unroll
        for (int k = 0; k < 4; ++k) {
            bf16x8 a[2];
            a[0] = *(const bf16x8*)&Xs[lr][k * 32 + kg * 8];
            a[1] = *(const bf16x8*)&Xs[16 + lr][k * 32 + kg * 8];
            #pragma unroll
            for (int m = 0; m < 2; ++m)
                #pragma unroll
                for (int nn = 0; nn < 4; ++nn)
                    acc[m][nn] = __builtin_amdgcn_mfma_f32_16x16x32_bf16(a[m], ball[k][nn], acc[m][nn], 0, 0, 0);
        }
        #pragma unroll
        for (int nn = 0; nn < 4; ++nn) {
            float bb = b1[n0 + nn * 16 + lr];
            #pragma unroll
            for (int m = 0; m < 2; ++m)
                #pragma unroll
                for (int r = 0; r < 4; ++r)
                    H1s[m * 16 + kg * 4 + r][n0 + nn * 16 + lr] = f2bf(fmaxf(acc[m][nn][r] + bb, 0.f));
        }
    }

    int r0 = (w & 1) * 16, c0 = (w >> 1) * 32;
    bf16x8 ball2[8][2];
    #pragma unroll
    for (int k = 0; k < 8; ++k)
        #pragma unroll
        for (int nn = 0; nn < 2; ++nn)
            ball2[k][nn] = *(const bf16x8*)(W2T + (size_t)(c0 + nn * 16 + lr) * HIDDEN + k * 32 + kg * 8);
    __syncthreads();

    {
        f32x4 acc2[2];
        acc2[0] = (f32x4){0.f, 0.f, 0.f, 0.f};
        acc2[1] = (f32x4){0.f, 0.f, 0.f, 0.f};
        #pragma unroll
        for (int k = 0; k < 8; ++k) {
            bf16x8 a = *(const bf16x8*)&H1s[r0 + lr][k * 32 + kg * 8];
            acc2[0] = __builtin_amdgcn_mfma_f32_16x16x32_bf16(a, ball2[k][0], acc2[0], 0, 0, 0);
            acc2[1] = __builtin_amdgcn_mfma_f32_16x16x32_bf16(a, ball2[k][1], acc2[1], 0, 0, 0);
        }
        #pragma unroll
        for (int nn = 0; nn < 2; ++nn) {
            float bb = b2[c0 + nn * 16 + lr];
            #pragma unroll
            for (int r = 0; r < 4; ++r) {
                int rw = rowBase + r0 + kg * 4 + r;
                if (rw < n) {
                    float val = acc2[nn][r] + bb;
                    size_t idx = (size_t)rw * EMBED + c0 + nn * 16 + lr;
                    x0bf[idx] = f2bf(val);
                    g0bf[idx] = f2bf(dinv[rw] * val);
                }
            }
        }
    }
}

// ---- pass B: bin edges by dst bucket into tile-private slots (LDS cursors only) ----
__global__ __launch_bounds__(256) void bin_edges(
    const int* __restrict__ row, const int* __restrict__ col,
    u32* __restrict__ slot, int* __restrict__ slotcnt, int e)
{
    __shared__ int bcur[NBUCK];
    int t = threadIdx.x;
    if (t < NBUCK) bcur[t] = 0;
    __syncthreads();
    int base = blockIdx.x * TILE;
    for (int i = t; i < TILE; i += 256) {
        int gi = base + i;
        if (gi >= e) break;
        int c = col[gi], r = row[gi];
        int b = c >> NPB_SHIFT;
        int pos = atomicAdd(&bcur[b], 1);
        if (pos < CAP)
            slot[((size_t)blockIdx.x * NBUCK + b) * CAP + pos] =
                (u32)r | ((u32)(c & (NPB - 1)) << 17);
    }
    __syncthreads();
    if (t < NBUCK) slotcnt[blockIdx.x * NBUCK + t] = min(bcur[t], CAP);
}

// ---- per-bucket tile-count reduction (98 blocks x 256 thr) ----
__global__ __launch_bounds__(256) void bucket_sums(const int* __restrict__ slotcnt,
                                                   int* __restrict__ bsum)
{
    __shared__ int sh[256];
    int b = blockIdx.x, t = threadIdx.x;
    int s = 0;
    for (int tile = t; tile < NTILES; tile += 256) s += slotcnt[tile * NBUCK + b];
    sh[t] = s; __syncthreads();
    for (int o = 128; o > 0; o >>= 1) {
        if (t < o) sh[t] += sh[t + o];
        __syncthreads();
    }
    if (t == 0) bsum[b] = sh[0];
}
// ---- tiny exclusive scan over 98 bucket sums ----
__global__ void scan_bucket_base(const int* __restrict__ bsum,
                                 int* __restrict__ bucket_base, int* __restrict__ off)
{
    if (threadIdx.x == 0) {
        int run = 0;
        for (int b = 0; b < NBUCK; ++b) { bucket_base[b] = run; run += bsum[b]; }
        off[N_NODES] = run;
    }
}

// ---- pass C: count -> scan -> off/dinv -> per-bucket degree sort (perm) -> place ----
__global__ __launch_bounds__(1024) void csc_from_bins(
    const u32* __restrict__ slot, const int* __restrict__ slotcnt,
    const int* __restrict__ bucket_base,
    int* __restrict__ off, float* __restrict__ dinv, int* __restrict__ ew,
    int* __restrict__ perm)
{
    __shared__ int cnt[NPB];
    __shared__ int sA[NPB];
    __shared__ int sB[NPB];
    __shared__ int h64[64];
    __shared__ int hcur[64];
    int b = blockIdx.x, t = threadIdx.x;
    int vbase = b << NPB_SHIFT;
    int nv = min(NPB, N_NODES - vbase);
    int wid = t >> 5, lane = t & 31;   // 32 sub-groups of 32 lanes

    cnt[t] = 0;
    if (t < 64) { h64[t] = 0; hcur[t] = 0; }
    __syncthreads();
    for (int tile = wid; tile < NTILES; tile += 32) {
        int n_tb = slotcnt[tile * NBUCK + b];
        const u32* seg = slot + ((size_t)tile * NBUCK + b) * CAP;
        for (int i = lane; i < n_tb; i += 32)
            atomicAdd(&cnt[seg[i] >> 17], 1);
    }
    __syncthreads();
    sA[t] = cnt[t];
    __syncthreads();
    int* src = sA; int* dst = sB;
    #pragma unroll
    for (int o = 1; o < NPB; o <<= 1) {
        dst[t] = src[t] + ((t >= o) ? src[t - o] : 0);
        __syncthreads();
        int* tmp = src; src = dst; dst = tmp;
    }
    int bb = bucket_base[b];
    int c  = cnt[t];
    int o  = bb + src[t] - c;   // exclusive offset
    int dcl = (c > 63) ? 63 : c;
    if (t < nv) {
        off[vbase + t]  = o;
        dinv[vbase + t] = rsqrtf((float)(c + 1));
        atomicAdd(&h64[dcl], 1);        // degree histogram for per-bucket sort
    }
    __syncthreads();
    if (t == 0) {                       // exclusive scan of 64-bin histogram
        int run = 0;
        #pragma unroll
        for (int d = 0; d < 64; ++d) { int tmp = h64[d]; h64[d] = run; run += tmp; }
    }
    __syncthreads();
    if (t < nv) {                       // perm: bucket-aligned degree-sorted ranks
        int r = h64[dcl] + atomicAdd(&hcur[dcl], 1);
        perm[vbase + r] = vbase + t;
    }
    cnt[t] = o;                         // cnt becomes cursor (after scan reads done)
    __syncthreads();
    for (int tile = wid; tile < NTILES; tile += 32) {
        int n_tb = slotcnt[tile * NBUCK + b];
        const u32* seg = slot + ((size_t)tile * NBUCK + b) * CAP;
        for (int i = lane; i < n_tb; i += 32) {
            u32 u = seg[i];
            int p = atomicAdd(&cnt[u >> 17], 1);
            ew[p] = (int)(u & 0x1FFFFu);
        }
    }
}

// ---------------- propagation: pull, 8 lanes/node x 16B/lane, degree-sorted rank order ----------------
__global__ __launch_bounds__(256) void prop8(
    const int* __restrict__ off, const int* __restrict__ ew,
    const u32* __restrict__ gin, const u32* __restrict__ x0,
    const float* __restrict__ dinv, const int* __restrict__ perm,
    u32* __restrict__ gout, float* __restrict__ hout, int final_step)
{
    int t = threadIdx.x;
    int rank = blockIdx.x * 32 + (t >> 3);   // grid exact: 3125*32 = 100000
    int v = perm[rank];                      // wave's 8 nodes have ~equal degree
    int l = t & 7;
    const u32* base = gin + l * 4;
    int s = off[v], e = off[v + 1];

    float aL0 = 0.f, aH0 = 0.f, aL1 = 0.f, aH1 = 0.f;
    float aL2 = 0.f, aH2 = 0.f, aL3 = 0.f, aH3 = 0.f;

    int i = s;
    int pre = (4 - (s & 3)) & 3;
    if (pre > e - s) pre = e - s;
    for (int k = 0; k < pre; ++k, ++i) {
        uint4 r = *(const uint4*)(base + (size_t)ew[i] * 32);
        aL0 += bflo(r.x); aH0 += bfhi(r.x);
        aL1 += bflo(r.y); aH1 += bfhi(r.y);
        aL2 += bflo(r.z); aH2 += bfhi(r.z);
        aL3 += bflo(r.w); aH3 += bfhi(r.w);
    }
    for (; i + 4 <= e; i += 4) {
        int4 e4 = *(const int4*)(ew + i);
        uint4 r0 = *(const uint4*)(base + (size_t)e4.x * 32);
        uint4 r1 = *(const uint4*)(base + (size_t)e4.y * 32);
        uint4 r2 = *(const uint4*)(base + (size_t)e4.z * 32);
        uint4 r3 = *(const uint4*)(base + (size_t)e4.w * 32);
        aL0 += (bflo(r0.x) + bflo(r1.x)) + (bflo(r2.x) + bflo(r3.x));
        aH0 += (bfhi(r0.x) + bfhi(r1.x)) + (bfhi(r2.x) + bfhi(r3.x));
        aL1 += (bflo(r0.y) + bflo(r1.y)) + (bflo(r2.y) + bflo(r3.y));
        aH1 += (bfhi(r0.y) + bfhi(r1.y)) + (bfhi(r2.y) + bfhi(r3.y));
        aL2 += (bflo(r0.z) + bflo(r1.z)) + (bflo(r2.z) + bflo(r3.z));
        aH2 += (bfhi(r0.z) + bfhi(r1.z)) + (bfhi(r2.z) + bfhi(r3.z));
        aL3 += (bflo(r0.w) + bflo(r1.w)) + (bflo(r2.w) + bflo(r3.w));
        aH3 += (bfhi(r0.w) + bfhi(r1.w)) + (bfhi(r2.w) + bfhi(r3.w));
    }
    for (; i < e; ++i) {
        uint4 r = *(const uint4*)(base + (size_t)ew[i] * 32);
        aL0 += bflo(r.x); aH0 += bfhi(r.x);
        aL1 += bflo(r.y); aH1 += bfhi(r.y);
        aL2 += bflo(r.z); aH2 += bfhi(r.z);
        aL3 += bflo(r.w); aH3 += bfhi(r.w);
    }

    uint4 rs = *(const uint4*)(base + (size_t)v * 32);
    uint4 rx = *(const uint4*)(x0 + (size_t)v * 32 + l * 4);
    float dv = dinv[v];
    float h0 = 0.9f * dv * (aL0 + bflo(rs.x)) + 0.1f * bflo(rx.x);
    float h1 = 0.9f * dv * (aH0 + bfhi(rs.x)) + 0.1f * bfhi(rx.x);
    float h2 = 0.9f * dv * (aL1 + bflo(rs.y)) + 0.1f * bflo(rx.y);
    float h3 = 0.9f * dv * (aH1 + bfhi(rs.y)) + 0.1f * bfhi(rx.y);
    float h4 = 0.9f * dv * (aL2 + bflo(rs.z)) + 0.1f * bflo(rx.z);
    float h5 = 0.9f * dv * (aH2 + bfhi(rs.z)) + 0.1f * bfhi(rx.z);
    float h6 = 0.9f * dv * (aL3 + bflo(rs.w)) + 0.1f * bflo(rx.w);
    float h7 = 0.9f * dv * (aH3 + bfhi(rs.w)) + 0.1f * bfhi(rx.w);

    if (final_step) {
        float* o = hout + (size_t)v * EMBED + l * 8;
        *(float4*)(o)     = make_float4(h0, h1, h2, h3);
        *(float4*)(o + 4) = make_float4(h4, h5, h6, h7);
    } else {
        uint4 g;
        g.x = (u32)f2bf(dv * h0) | ((u32)f2bf(dv * h1) << 16);
        g.y = (u32)f2bf(dv * h2) | ((u32)f2bf(dv * h3) << 16);
        g.z = (u32)f2bf(dv * h4) | ((u32)f2bf(dv * h5) << 16);
        g.w = (u32)f2bf(dv * h6) | ((u32)f2bf(dv * h7) << 16);
        *(uint4*)(gout + (size_t)v * 32 + l * 4) = g;
    }
}

extern "C" void kernel_launch(void* const* d_in, const int* in_sizes, int n_in,
                              void* d_out, int out_size, void* d_ws, size_t ws_size,
                              hipStream_t stream)
{
    const float* x  = (const float*)d_in[0];
    const int*   ei = (const int*)d_in[1];
    const float* W1 = (const float*)d_in[2];
    const float* b1 = (const float*)d_in[3];
    const float* W2 = (const float*)d_in[4];
    const float* b2 = (const float*)d_in[5];
    float* out = (float*)d_out;
    const int* row = ei;
    const int* col = ei + N_EDGES;

    // permanent carve-out (~47 MB)
    char* w = (char*)d_ws;
    u16* x0bf = (u16*)w; w += (size_t)N_NODES * EMBED * 2;   // 12.8 MB
    u16* gA   = (u16*)w; w += (size_t)N_NODES * EMBED * 2;   // 12.8 MB (x0bf+gA = alias region)
    u16* gB   = (u16*)w; w += (size_t)N_NODES * EMBED * 2;   // 12.8 MB
    int* ew   = (int*)w;  w += (size_t)N_EDGES * 4;          // 6.4 MB
    int* off  = (int*)w;  w += ((size_t)(N_NODES + 1) * 4 + 12) & ~15ull;
    int* bucket_base = (int*)w; w += 2048;
    int* bsum = (int*)w; w += 2048;
    float* dinv = (float*)w; w += (size_t)N_NODES * 4;
    int* perm = (int*)w; w += (size_t)N_NODES * 4;           // 400 KB
    u16* W1T = (u16*)w; w += (size_t)IN_DIM * HIDDEN * 2;
    u16* W2T = (u16*)w; w += (size_t)HIDDEN * EMBED * 2;

    // transient binning storage aliased onto x0bf+gA (dead until mlp_mfma runs)
    u32* slot    = (u32*)x0bf;                                     // 19.62 MB
    int* slotcnt = (int*)((char*)x0bf + (size_t)NTILES * NBUCK * CAP * 4);  // +306 KB

    conv_weights<<<(IN_DIM * HIDDEN + HIDDEN * EMBED + 255) / 256, 256, 0, stream>>>(W1, W2, W1T, W2T);
    bin_edges<<<NTILES, 256, 0, stream>>>(row, col, slot, slotcnt, N_EDGES);
    bucket_sums<<<NBUCK, 256, 0, stream>>>(slotcnt, bsum);
    scan_bucket_base<<<1, 64, 0, stream>>>(bsum, bucket_base, off);
    csc_from_bins<<<NBUCK, 1024, 0, stream>>>(slot, slotcnt, bucket_base, off, dinv, ew, perm);

    // MLP after binning (slots alias x0bf/gA); needs dinv (from csc_from_bins)
    mlp_mfma<<<(N_NODES + 31) / 32, 256, 0, stream>>>(x, W1T, b1, W2T, b2, dinv, x0bf, gA, N_NODES);

    // K=10 steps, degree-sorted rank order
    const u32* gin = (const u32*)gA;
    for (int s = 0; s < K_STEPS; ++s) {
        int fin = (s == K_STEPS - 1);
        u32* gout = (u32*)((s & 1) ? gA : gB);
        prop8<<<N_NODES / 32, 256, 0, stream>>>(off, ew, gin, (const u32*)x0bf, dinv,
                                                perm, gout, out, fin);
        gin = gout;
    }
}

// Round 13
// 432.095 us; speedup vs baseline: 1.1772x; 1.1772x over previous
//
#include <hip/hip_runtime.h>

#define N_NODES 100000
#define N_EDGES 1600000
#define IN_DIM 128
#define HIDDEN 256
#define EMBED 64
#define K_STEPS 10

// binning geometry
#define NPB_SHIFT 10
#define NPB 1024                    // nodes per bucket
#define NBUCK 98                    // ceil(100000/1024)
#define TILE 2048                   // edges per bin tile
#define NTILES 782                  // ceil(1.6M/2048)
#define CAP 64                      // slots per (tile,bucket); mean 20.9 -> 9.6 sigma margin

typedef unsigned int u32;
typedef unsigned short u16;
using bf16x8 = __attribute__((ext_vector_type(8))) short;
using f32x4  = __attribute__((ext_vector_type(4))) float;

__device__ __forceinline__ float bflo(u32 u) { return __uint_as_float(u << 16); }
__device__ __forceinline__ float bfhi(u32 u) { return __uint_as_float(u & 0xffff0000u); }
__device__ __forceinline__ u16 f2bf(float f) {   // round-to-nearest-even
    u32 u = __float_as_uint(f);
    u += 0x7fffu + ((u >> 16) & 1u);
    return (u16)(u >> 16);
}

// ---------------- weight prep: transpose + bf16 convert ----------------
__global__ void conv_weights(const float* __restrict__ W1, const float* __restrict__ W2,
                             u16* __restrict__ W1T, u16* __restrict__ W2T)
{
    int i = blockIdx.x * 256 + threadIdx.x;
    if (i < IN_DIM * HIDDEN) {
        int n = i / IN_DIM, k = i % IN_DIM;
        W1T[i] = f2bf(W1[k * HIDDEN + n]);
    }
    int j = i - IN_DIM * HIDDEN;
    if (j >= 0 && j < HIDDEN * EMBED) {
        int n = j / HIDDEN, k = j % HIDDEN;
        W2T[j] = f2bf(W2[k * EMBED + n]);
    }
}

// ---------------- fused MLP via bf16 MFMA; 32-row tile (frozen) ----------------
__global__ __launch_bounds__(256) void mlp_mfma(
    const float* __restrict__ x, const u16* __restrict__ W1T,
    const float* __restrict__ b1, const u16* __restrict__ W2T,
    const float* __restrict__ b2, const float* __restrict__ dinv,
    u16* __restrict__ x0bf, u16* __restrict__ g0bf, int n)
{
    __shared__ u16 Xs[32][136];    // 8.7 KB
    __shared__ u16 H1s[32][264];   // 16.9 KB
    int t = threadIdx.x;
    int rowBase = blockIdx.x * 32;
    int lane = t & 63, w = t >> 6;
    int lr = lane & 15, kg = lane >> 4;

    {
        float4 v[4];
        #pragma unroll
        for (int it = 0; it < 4; ++it) {
            int i = t + it * 256;
            int row = i >> 5, c4 = (i & 31) * 4;
            v[it] = make_float4(0.f, 0.f, 0.f, 0.f);
            if (rowBase + row < n)
                v[it] = *(const float4*)(x + (size_t)(rowBase + row) * IN_DIM + c4);
        }
        #pragma unroll
        for (int it = 0; it < 4; ++it) {
            int i = t + it * 256;
            int row = i >> 5, c4 = (i & 31) * 4;
            Xs[row][c4 + 0] = f2bf(v[it].x); Xs[row][c4 + 1] = f2bf(v[it].y);
            Xs[row][c4 + 2] = f2bf(v[it].z); Xs[row][c4 + 3] = f2bf(v[it].w);
        }
    }

    int n0 = w * 64;
    bf16x8 ball[4][4];
    #pragma unroll
    for (int k = 0; k < 4; ++k)
        #pragma unroll
        for (int nn = 0; nn < 4; ++nn)
            ball[k][nn] = *(const bf16x8*)(W1T + (size_t)(n0 + nn * 16 + lr) * IN_DIM + k * 32 + kg * 8);
    __syncthreads();

    {
        f32x4 acc[2][4];
        #pragma unroll
        for (int m = 0; m < 2; ++m)
            #pragma unroll
            for (int nn = 0; nn < 4; ++nn) acc[m][nn] = (f32x4){0.f, 0.f, 0.f, 0.f};
        #pragma unroll
        for (int k = 0; k < 4; ++k) {
            bf16x8 a[2];
            a[0] = *(const bf16x8*)&Xs[lr][k * 32 + kg * 8];
            a[1] = *(const bf16x8*)&Xs[16 + lr][k * 32 + kg * 8];
            #pragma unroll
            for (int m = 0; m < 2; ++m)
                #pragma unroll
                for (int nn = 0; nn < 4; ++nn)
                    acc[m][nn] = __builtin_amdgcn_mfma_f32_16x16x32_bf16(a[m], ball[k][nn], acc[m][nn], 0, 0, 0);
        }
        #pragma unroll
        for (int nn = 0; nn < 4; ++nn) {
            float bb = b1[n0 + nn * 16 + lr];
            #pragma unroll
            for (int m = 0; m < 2; ++m)
                #pragma unroll
                for (int r = 0; r < 4; ++r)
                    H1s[m * 16 + kg * 4 + r][n0 + nn * 16 + lr] = f2bf(fmaxf(acc[m][nn][r] + bb, 0.f));
        }
    }

    int r0 = (w & 1) * 16, c0 = (w >> 1) * 32;
    bf16x8 ball2[8][2];
    #pragma unroll
    for (int k = 0; k < 8; ++k)
        #pragma unroll
        for (int nn = 0; nn < 2; ++nn)
            ball2[k][nn] = *(const bf16x8*)(W2T + (size_t)(c0 + nn * 16 + lr) * HIDDEN + k * 32 + kg * 8);
    __syncthreads();

    {
        f32x4 acc2[2];
        acc2[0] = (f32x4){0.f, 0.f, 0.f, 0.f};
        acc2[1] = (f32x4){0.f, 0.f, 0.f, 0.f};
        #pragma unroll
        for (int k = 0; k < 8; ++k) {
            bf16x8 a = *(const bf16x8*)&H1s[r0 + lr][k * 32 + kg * 8];
            acc2[0] = __builtin_amdgcn_mfma_f32_16x16x32_bf16(a, ball2[k][0], acc2[0], 0, 0, 0);
            acc2[1] = __builtin_amdgcn_mfma_f32_16x16x32_bf16(a, ball2[k][1], acc2[1], 0, 0, 0);
        }
        #pragma unroll
        for (int nn = 0; nn < 2; ++nn) {
            float bb = b2[c0 + nn * 16 + lr];
            #pragma unroll
            for (int r = 0; r < 4; ++r) {
                int rw = rowBase + r0 + kg * 4 + r;
                if (rw < n) {
                    float val = acc2[nn][r] + bb;
                    size_t idx = (size_t)rw * EMBED + c0 + nn * 16 + lr;
                    x0bf[idx] = f2bf(val);
                    g0bf[idx] = f2bf(dinv[rw] * val);
                }
            }
        }
    }
}

// ---- pass B: bin edges by dst bucket into tile-private slots (LDS cursors only) ----
__global__ __launch_bounds__(256) void bin_edges(
    const int* __restrict__ row, const int* __restrict__ col,
    u32* __restrict__ slot, int* __restrict__ slotcnt, int e)
{
    __shared__ int bcur[NBUCK];
    int t = threadIdx.x;
    if (t < NBUCK) bcur[t] = 0;
    __syncthreads();
    int base = blockIdx.x * TILE;
    for (int i = t; i < TILE; i += 256) {
        int gi = base + i;
        if (gi >= e) break;
        int c = col[gi], r = row[gi];
        int b = c >> NPB_SHIFT;
        int pos = atomicAdd(&bcur[b], 1);
        if (pos < CAP)
            slot[((size_t)blockIdx.x * NBUCK + b) * CAP + pos] =
                (u32)r | ((u32)(c & (NPB - 1)) << 17);
    }
    __syncthreads();
    if (t < NBUCK) slotcnt[blockIdx.x * NBUCK + t] = min(bcur[t], CAP);
}

// ---- per-bucket tile-count reduction (98 blocks x 256 thr) ----
__global__ __launch_bounds__(256) void bucket_sums(const int* __restrict__ slotcnt,
                                                   int* __restrict__ bsum)
{
    __shared__ int sh[256];
    int b = blockIdx.x, t = threadIdx.x;
    int s = 0;
    for (int tile = t; tile < NTILES; tile += 256) s += slotcnt[tile * NBUCK + b];
    sh[t] = s; __syncthreads();
    for (int o = 128; o > 0; o >>= 1) {
        if (t < o) sh[t] += sh[t + o];
        __syncthreads();
    }
    if (t == 0) bsum[b] = sh[0];
}
// ---- tiny exclusive scan over 98 bucket sums ----
__global__ void scan_bucket_base(const int* __restrict__ bsum,
                                 int* __restrict__ bucket_base, int* __restrict__ off)
{
    if (threadIdx.x == 0) {
        int run = 0;
        for (int b = 0; b < NBUCK; ++b) { bucket_base[b] = run; run += bsum[b]; }
        off[N_NODES] = run;
    }
}

// ---- pass C: count (LDS) -> scan (LDS) -> off/dinv -> place; 32-lane sub-wave drains ----
__global__ __launch_bounds__(1024) void csc_from_bins(
    const u32* __restrict__ slot, const int* __restrict__ slotcnt,
    const int* __restrict__ bucket_base,
    int* __restrict__ off, float* __restrict__ dinv, int* __restrict__ ew)
{
    __shared__ int cnt[NPB];
    __shared__ int sA[NPB];
    __shared__ int sB[NPB];
    int b = blockIdx.x, t = threadIdx.x;
    int vbase = b << NPB_SHIFT;
    int nv = min(NPB, N_NODES - vbase);
    int wid = t >> 5, lane = t & 31;   // 32 sub-groups of 32 lanes

    cnt[t] = 0;
    __syncthreads();
    for (int tile = wid; tile < NTILES; tile += 32) {
        int n_tb = slotcnt[tile * NBUCK + b];
        const u32* seg = slot + ((size_t)tile * NBUCK + b) * CAP;
        for (int i = lane; i < n_tb; i += 32)
            atomicAdd(&cnt[seg[i] >> 17], 1);
    }
    __syncthreads();
    sA[t] = cnt[t];
    __syncthreads();
    int* src = sA; int* dst = sB;
    #pragma unroll
    for (int o = 1; o < NPB; o <<= 1) {
        dst[t] = src[t] + ((t >= o) ? src[t - o] : 0);
        __syncthreads();
        int* tmp = src; src = dst; dst = tmp;
    }
    int bb = bucket_base[b];
    int c  = cnt[t];
    int o  = bb + src[t] - c;   // exclusive offset
    if (t < nv) {
        off[vbase + t]  = o;
        dinv[vbase + t] = rsqrtf((float)(c + 1));
    }
    __syncthreads();
    cnt[t] = o;                 // cnt becomes cursor
    __syncthreads();
    for (int tile = wid; tile < NTILES; tile += 32) {
        int n_tb = slotcnt[tile * NBUCK + b];
        const u32* seg = slot + ((size_t)tile * NBUCK + b) * CAP;
        for (int i = lane; i < n_tb; i += 32) {
            u32 u = seg[i];
            int p = atomicAdd(&cnt[u >> 17], 1);
            ew[p] = (int)(u & 0x1FFFFu);
        }
    }
}

// ---------------- propagation: pull, 8 lanes/node x 16B/lane, unroll x4 + e4 prefetch ----------------
__global__ __launch_bounds__(256) void prop8(
    const int* __restrict__ off, const int* __restrict__ ew,
    const u32* __restrict__ gin, const u32* __restrict__ x0,
    const float* __restrict__ dinv,
    u32* __restrict__ gout, float* __restrict__ hout, int final_step)
{
    int t = threadIdx.x;
    int v = blockIdx.x * 32 + (t >> 3);   // grid exact: 3125*32 = 100000
    int l = t & 7;
    const u32* base = gin + l * 4;
    int s = off[v], e = off[v + 1];

    float aL0 = 0.f, aH0 = 0.f, aL1 = 0.f, aH1 = 0.f;
    float aL2 = 0.f, aH2 = 0.f, aL3 = 0.f, aH3 = 0.f;

    auto one = [&](int src) {
        uint4 r = *(const uint4*)(base + (size_t)src * 32);
        aL0 += bflo(r.x); aH0 += bfhi(r.x);
        aL1 += bflo(r.y); aH1 += bfhi(r.y);
        aL2 += bflo(r.z); aH2 += bfhi(r.z);
        aL3 += bflo(r.w); aH3 += bfhi(r.w);
    };
    auto quad = [&](int4 e4) {
        uint4 r0 = *(const uint4*)(base + (size_t)e4.x * 32);
        uint4 r1 = *(const uint4*)(base + (size_t)e4.y * 32);
        uint4 r2 = *(const uint4*)(base + (size_t)e4.z * 32);
        uint4 r3 = *(const uint4*)(base + (size_t)e4.w * 32);
        aL0 += (bflo(r0.x) + bflo(r1.x)) + (bflo(r2.x) + bflo(r3.x));
        aH0 += (bfhi(r0.x) + bfhi(r1.x)) + (bfhi(r2.x) + bfhi(r3.x));
        aL1 += (bflo(r0.y) + bflo(r1.y)) + (bflo(r2.y) + bflo(r3.y));
        aH1 += (bfhi(r0.y) + bfhi(r1.y)) + (bfhi(r2.y) + bfhi(r3.y));
        aL2 += (bflo(r0.z) + bflo(r1.z)) + (bflo(r2.z) + bflo(r3.z));
        aH2 += (bfhi(r0.z) + bfhi(r1.z)) + (bfhi(r2.z) + bfhi(r3.z));
        aL3 += (bflo(r0.w) + bflo(r1.w)) + (bflo(r2.w) + bflo(r3.w));
        aH3 += (bfhi(r0.w) + bfhi(r1.w)) + (bfhi(r2.w) + bfhi(r3.w));
    };

    int i = s;
    int pre = (4 - (s & 3)) & 3;          // peel to 16B-align int4 edge loads
    if (pre > e - s) pre = e - s;
    for (int k = 0; k < pre; ++k, ++i) one(ew[i]);

    int nq = (e - i) >> 2;
    if (nq > 0) {
        int4 e4 = *(const int4*)(ew + i);
        for (int q = 1; q < nq; ++q) {
            int4 e4n = *(const int4*)(ew + i + 4 * q);  // next quad in flight during accumulate
            quad(e4);
            e4 = e4n;
        }
        quad(e4);
        i += nq << 2;
    }
    for (; i < e; ++i) one(ew[i]);

    uint4 rs = *(const uint4*)(base + (size_t)v * 32);
    uint4 rx = *(const uint4*)(x0 + (size_t)v * 32 + l * 4);
    float dv = dinv[v];
    float h0 = 0.9f * dv * (aL0 + bflo(rs.x)) + 0.1f * bflo(rx.x);
    float h1 = 0.9f * dv * (aH0 + bfhi(rs.x)) + 0.1f * bfhi(rx.x);
    float h2 = 0.9f * dv * (aL1 + bflo(rs.y)) + 0.1f * bflo(rx.y);
    float h3 = 0.9f * dv * (aH1 + bfhi(rs.y)) + 0.1f * bfhi(rx.y);
    float h4 = 0.9f * dv * (aL2 + bflo(rs.z)) + 0.1f * bflo(rx.z);
    float h5 = 0.9f * dv * (aH2 + bfhi(rs.z)) + 0.1f * bfhi(rx.z);
    float h6 = 0.9f * dv * (aL3 + bflo(rs.w)) + 0.1f * bflo(rx.w);
    float h7 = 0.9f * dv * (aH3 + bfhi(rs.w)) + 0.1f * bfhi(rx.w);

    if (final_step) {
        float* o = hout + (size_t)v * EMBED + l * 8;
        *(float4*)(o)     = make_float4(h0, h1, h2, h3);
        *(float4*)(o + 4) = make_float4(h4, h5, h6, h7);
    } else {
        uint4 g;
        g.x = (u32)f2bf(dv * h0) | ((u32)f2bf(dv * h1) << 16);
        g.y = (u32)f2bf(dv * h2) | ((u32)f2bf(dv * h3) << 16);
        g.z = (u32)f2bf(dv * h4) | ((u32)f2bf(dv * h5) << 16);
        g.w = (u32)f2bf(dv * h6) | ((u32)f2bf(dv * h7) << 16);
        *(uint4*)(gout + (size_t)v * 32 + l * 4) = g;
    }
}

extern "C" void kernel_launch(void* const* d_in, const int* in_sizes, int n_in,
                              void* d_out, int out_size, void* d_ws, size_t ws_size,
                              hipStream_t stream)
{
    const float* x  = (const float*)d_in[0];
    const int*   ei = (const int*)d_in[1];
    const float* W1 = (const float*)d_in[2];
    const float* b1 = (const float*)d_in[3];
    const float* W2 = (const float*)d_in[4];
    const float* b2 = (const float*)d_in[5];
    float* out = (float*)d_out;
    const int* row = ei;
    const int* col = ei + N_EDGES;

    // permanent carve-out (~46 MB)
    char* w = (char*)d_ws;
    u16* x0bf = (u16*)w; w += (size_t)N_NODES * EMBED * 2;   // 12.8 MB
    u16* gA   = (u16*)w; w += (size_t)N_NODES * EMBED * 2;   // 12.8 MB (x0bf+gA = alias region)
    u16* gB   = (u16*)w; w += (size_t)N_NODES * EMBED * 2;   // 12.8 MB
    int* ew   = (int*)w;  w += (size_t)N_EDGES * 4;          // 6.4 MB
    int* off  = (int*)w;  w += ((size_t)(N_NODES + 1) * 4 + 12) & ~15ull;
    int* bucket_base = (int*)w; w += 2048;
    int* bsum = (int*)w; w += 2048;
    float* dinv = (float*)w; w += (size_t)N_NODES * 4;
    u16* W1T = (u16*)w; w += (size_t)IN_DIM * HIDDEN * 2;
    u16* W2T = (u16*)w; w += (size_t)HIDDEN * EMBED * 2;

    // transient binning storage aliased onto x0bf+gA (dead until mlp_mfma runs)
    u32* slot    = (u32*)x0bf;                                     // 19.62 MB
    int* slotcnt = (int*)((char*)x0bf + (size_t)NTILES * NBUCK * CAP * 4);  // +306 KB

    conv_weights<<<(IN_DIM * HIDDEN + HIDDEN * EMBED + 255) / 256, 256, 0, stream>>>(W1, W2, W1T, W2T);
    bin_edges<<<NTILES, 256, 0, stream>>>(row, col, slot, slotcnt, N_EDGES);
    bucket_sums<<<NBUCK, 256, 0, stream>>>(slotcnt, bsum);
    scan_bucket_base<<<1, 64, 0, stream>>>(bsum, bucket_base, off);
    csc_from_bins<<<NBUCK, 1024, 0, stream>>>(slot, slotcnt, bucket_base, off, dinv, ew);

    // MLP after binning (slots alias x0bf/gA); needs dinv (from csc_from_bins)
    mlp_mfma<<<(N_NODES + 31) / 32, 256, 0, stream>>>(x, W1T, b1, W2T, b2, dinv, x0bf, gA, N_NODES);

    // K=10 steps
    const u32* gin = (const u32*)gA;
    for (int s = 0; s < K_STEPS; ++s) {
        int fin = (s == K_STEPS - 1);
        u32* gout = (u32*)((s & 1) ? gA : gB);
        prop8<<<N_NODES / 32, 256, 0, stream>>>(off, ew, gin, (const u32*)x0bf, dinv,
                                                gout, out, fin);
        gin = gout;
    }
}